// Round 6
// baseline (112.812 us; speedup 1.0000x reference)
//
#include <hip/hip_runtime.h>
#include <hip/hip_bf16.h>

// Problem constants (fixed by setup_inputs)
#define B_N 4096
#define D_K 512
#define INV_T 10.0f

// k1: SYMMETRIC decomposition at FULL 128x128 super-tiles (R5-verified).
// 528 blocks (C >= R). Off-diag tile (R,C): row-side reduce -> slot 2C
// (zero at 2C+1); col-side reduce over two 64-row i-halves -> slots 2R,2R+1.
// Diagonal: row-side only with self-exclusion. Exactly-once coverage.
//
// Round-6 change: LOAD WIDTH / MLP. k1 was ~40us across all prior variants
// (FLOPs, staging, tile width all changed nothing) -> L2-latency-bound:
// 160 dwordx2 loads/wave at 512B stride, ~2 waves/SIMD TLP (528-block grid).
// Fix: fp8 layout embF[g][lane][kc] makes each lane's 16 K-chunks contiguous
// 128 B -> fragments load as 8x global_load_dwordx4 (80 loads/wave, 4x bytes
// per load, natural 8-deep MLP). Same bytes, pure permutation; math identical.
#define BM 128            // rows per block (4 waves x 32 rows)
#define CPB 128           // cols per block
#define CS 64             // 64 column-split slots per row
#define NCG (CPB / 16)    // 8 col-groups per block
#define SLOTS 16          // positive slots per (row, slot)
#define NTILES 528        // 32*33/2 upper-triangle super-tiles

typedef __attribute__((ext_vector_type(4))) float float4v;  // f32x4 accumulator

// ws layout:
//   [0,        16384)    float termSum[4096]
//   [16384,    32768)    float cntF[4096]
//   [32768,  1081344)    float denomPart[4096][64]
//   [1081344,2129920)    int   posCnt[4096][64]
//   [2129920,18907136)   float posS[4096][64][16]
//   [18907136,+2MiB)     fp8   embF (lane-contiguous fragment order)
#define WS_TERS   0
#define WS_CNTF   16384
#define WS_DENOM  32768
#define WS_POSCNT 1081344
#define WS_POSS   2129920
#define WS_EMBF   18907136

// ---------------- k0: fp32 -> fp8 e4m3 convert into lane-contiguous order ----
// Thread t -> (g = t>>10, lane = (t>>4)&63, kc = t&15): writes consecutive
// 8 B chunks (fully coalesced). Chunk (g,lane,kc) holds row g*16+(lane&15),
// k-bytes (kc*4 + (lane>>4))*8 .. +8  (identical data to old fragment order).
__global__ __launch_bounds__(256) void k0_convert(const float* __restrict__ emb,
                                                  unsigned char* __restrict__ embF) {
    int t    = blockIdx.x * 256 + threadIdx.x;   // 262144 threads total
    int kc   = t & 15;
    int lane = (t >> 4) & 63;
    int g    = t >> 10;
    int l16  = lane & 15;
    int quad = lane >> 4;
    int row  = g * 16 + l16;
    int kq   = kc * 4 + quad;
    const float* sp = emb + row * D_K + kq * 8;
    float4 v0 = *(const float4*)(sp);
    float4 v1 = *(const float4*)(sp + 4);
    int lo = __builtin_amdgcn_cvt_pk_fp8_f32(v0.x, v0.y, 0, false);
    lo     = __builtin_amdgcn_cvt_pk_fp8_f32(v0.z, v0.w, lo, true);
    int hi = __builtin_amdgcn_cvt_pk_fp8_f32(v1.x, v1.y, 0, false);
    hi     = __builtin_amdgcn_cvt_pk_fp8_f32(v1.z, v1.w, hi, true);
    int2 o; o.x = lo; o.y = hi;
    *(int2*)(embF + ((size_t)(g * 64 + lane) * 16 + kc) * 8) = o;
}

// ---------------- k1: symmetric fused sims + denom partials + positives ------
// Barrier-free main loop; A resident in VGPRs; A/B fragments loaded as
// 8x dwordx4 (128 B contiguous per lane) straight from L2-hot embF.
__global__ __launch_bounds__(256, 2) void k1_denom(const unsigned char* __restrict__ embF,
                                                   const int* __restrict__ labels,
                                                   float* __restrict__ denomPart,
                                                   int* __restrict__ posCnt,
                                                   float* __restrict__ posS) {
    __shared__ float sPos[BM * SLOTS];           // row-side positive slots   (8 KB)
    __shared__ int   sCnt[BM];
    __shared__ float sPosC[2 * CPB * SLOTS];     // col-side positive slots  (16 KB)
    __shared__ int   sCntC[2 * CPB];
    __shared__ float sColW[4 * CPB];             // per-wave column partial sums (2 KB)

    const int tid  = threadIdx.x;
    const int wave = tid >> 6;
    const int lane = tid & 63;
    const int quad = lane >> 4;
    const int l16  = lane & 15;

    // Triangular decode: tile t0 -> (R, C), C in [R, 32). Linear SALU scan.
    const int t0 = blockIdx.x;
    int R = 0, accT = 0;
    while (accT + (32 - R) <= t0) { accT += 32 - R; ++R; }
    const int C = R + (t0 - accT);
    const bool isDiag = (C == R);
    const int rowBase = R * BM;

    if (tid < BM) sCnt[tid] = 0;
    sCntC[tid] = 0;                              // 2*CPB == 256 == blockDim
    __syncthreads();   // counters visible before first positive-pair atomic

    // A fragments: 2 row-groups x 16 K-chunks -> 64 VGPRs, resident.
    // Per row-group: 128 B contiguous per lane -> 8x dwordx4.
    long afrag[2][16];
#pragma unroll
    for (int t = 0; t < 2; ++t) {
        const int g = R * 8 + wave * 2 + t;
        const unsigned char* ap = embF + (size_t)(g * 64 + lane) * 128;
#pragma unroll
        for (int i = 0; i < 8; ++i) {
            long2 v = *(const long2*)(ap + i * 16);
            afrag[t][2 * i]     = v.x;
            afrag[t][2 * i + 1] = v.y;
        }
    }

    int labI[2][4];
#pragma unroll
    for (int t = 0; t < 2; ++t)
#pragma unroll
        for (int r = 0; r < 4; ++r)
            labI[t][r] = labels[rowBase + wave * 32 + t * 16 + quad * 4 + r];

    int labJ[NCG];
#pragma unroll
    for (int cg = 0; cg < NCG; ++cg)
        labJ[cg] = labels[C * CPB + cg * 16 + l16];

    float rowAcc[2][4] = {{0.f,0.f,0.f,0.f},{0.f,0.f,0.f,0.f}};

#pragma unroll
    for (int cg = 0; cg < NCG; ++cg) {
        // B fragment: 128 B contiguous per lane -> 8x dwordx4, all in flight.
        const unsigned char* bp = embF + (size_t)((C * NCG + cg) * 64 + lane) * 128;
        long bfrag[16];
#pragma unroll
        for (int i = 0; i < 8; ++i) {
            long2 v = *(const long2*)(bp + i * 16);
            bfrag[2 * i]     = v.x;
            bfrag[2 * i + 1] = v.y;
        }

        float4v acc[2];
        acc[0] = (float4v){0.f, 0.f, 0.f, 0.f};
        acc[1] = (float4v){0.f, 0.f, 0.f, 0.f};
#pragma unroll
        for (int kc = 0; kc < 16; ++kc) {
            acc[0] = __builtin_amdgcn_mfma_f32_16x16x32_fp8_fp8(afrag[0][kc], bfrag[kc], acc[0], 0, 0, 0);
            acc[1] = __builtin_amdgcn_mfma_f32_16x16x32_fp8_fp8(afrag[1][kc], bfrag[kc], acc[1], 0, 0, 0);
        }

        const int col = C * CPB + cg * 16 + l16;
        const int lJ  = labJ[cg];
        float cAcc = 0.0f;     // col-side partial (this lane's 8 rows, column `col`)
#pragma unroll
        for (int t = 0; t < 2; ++t) {
#pragma unroll
            for (int r = 0; r < 4; ++r) {
                float s = acc[t][r] * INV_T;
                const int lr = wave * 32 + t * 16 + quad * 4 + r;
                if (lJ != labI[t][r]) {
                    float e = __expf(s);
                    rowAcc[t][r] += e;
                    cAcc += e;
                } else if (col != rowBase + lr) {           // positive pair
                    int idx = atomicAdd(&sCnt[lr], 1);
                    if (idx < SLOTS) sPos[lr * SLOTS + idx] = s;
                    if (!isDiag) {                          // transposed positive (j, i)
                        int ci = (wave >> 1) * CPB + cg * 16 + l16;
                        int idx2 = atomicAdd(&sCntC[ci], 1);
                        if (idx2 < SLOTS) sPosC[ci * SLOTS + idx2] = s;
                    }
                }
            }
        }
        if (!isDiag) {
            // reduce across the 4 quads (rows) -> per-wave column sum
            cAcc += __shfl_xor(cAcc, 16);
            cAcc += __shfl_xor(cAcc, 32);
            if (quad == 0) sColW[wave * CPB + cg * 16 + l16] = cAcc;
        }
    }

    // row-side: butterfly over the 16 l16-lanes -> denomPart[row][2C] (+zero odd)
#pragma unroll
    for (int t = 0; t < 2; ++t)
#pragma unroll
        for (int r = 0; r < 4; ++r) {
            float v = rowAcc[t][r];
            v += __shfl_xor(v, 1);
            v += __shfl_xor(v, 2);
            v += __shfl_xor(v, 4);
            v += __shfl_xor(v, 8);
            if (l16 == 0) {
                const int row = rowBase + wave * 32 + t * 16 + quad * 4 + r;
                denomPart[row * CS + 2 * C]     = v;
                denomPart[row * CS + 2 * C + 1] = 0.0f;
            }
        }

    __syncthreads();   // sPos/sCnt/sPosC/sCntC/sColW complete

    if (tid < BM) {                                   // row-side positive flush
        const int row = rowBase + tid;
        const int c   = min(sCnt[tid], SLOTS);
        posCnt[row * CS + 2 * C]     = c;
        posCnt[row * CS + 2 * C + 1] = 0;
        for (int m = 0; m < c; ++m)
            posS[(row * CS + 2 * C) * SLOTS + m] = sPos[tid * SLOTS + m];
    }
    if (!isDiag) {                                    // col-side flush (all 256 threads)
        const int s0 = tid >> 7;                      // which 64-row i-half -> slot 2R+s0
        const int cc = tid & (CPB - 1);               // column within tile
        const int j  = C * CPB + cc;                  // transposed row index
        const int sp = 2 * R + s0;
        denomPart[j * CS + sp] = sColW[(2 * s0) * CPB + cc] + sColW[(2 * s0 + 1) * CPB + cc];
        const int ci = s0 * CPB + cc;
        const int c  = min(sCntC[ci], SLOTS);
        posCnt[j * CS + sp] = c;
        for (int m = 0; m < c; ++m)
            posS[(j * CS + sp) * SLOTS + m] = sPosC[ci * SLOTS + m];
    }
}

// ---------------- k2: per-row positive terms (atomic-free) -------------------
__global__ __launch_bounds__(256) void k2_pos(const float* __restrict__ denomPart,
                                              const int* __restrict__ posCnt,
                                              const float* __restrict__ posS,
                                              float* __restrict__ termSum,
                                              float* __restrict__ cntF) {
    const int wave = threadIdx.x >> 6;
    const int lane = threadIdx.x & 63;
    const int i    = blockIdx.x * 4 + wave;

    float d  = denomPart[i * CS + lane];
    int   cb = posCnt[i * CS + lane];
    float c  = (float)cb;
#pragma unroll
    for (int off = 32; off; off >>= 1) {
        d += __shfl_xor(d, off);
        c += __shfl_xor(c, off);
    }

    float sum = 0.0f;
    const float* ps = posS + (i * CS + lane) * SLOTS;
    for (int m = 0; m < cb; ++m) {        // divergent; avg ~1 iter, max SLOTS
        float s = ps[m];
        sum += __logf(d + __expf(s)) - s;
    }
#pragma unroll
    for (int off = 32; off; off >>= 1) sum += __shfl_xor(sum, off);
    if (lane == 0) { termSum[i] = sum; cntF[i] = c; }
}

// ---------------- k3: single-block tree reduction ---------------------------
__global__ __launch_bounds__(256) void k3_final(const float* __restrict__ termSum,
                                                const float* __restrict__ cntF,
                                                float* __restrict__ out) {
    __shared__ float sL[256], sC[256];
    float ls = 0.0f, cs = 0.0f;
    for (int i = threadIdx.x; i < B_N; i += 256) { ls += termSum[i]; cs += cntF[i]; }
    sL[threadIdx.x] = ls; sC[threadIdx.x] = cs;
    __syncthreads();
    for (int s = 128; s; s >>= 1) {
        if (threadIdx.x < s) {
            sL[threadIdx.x] += sL[threadIdx.x + s];
            sC[threadIdx.x] += sC[threadIdx.x + s];
        }
        __syncthreads();
    }
    if (threadIdx.x == 0) out[0] = sL[0] / fmaxf(sC[0], 1.0f);
}

extern "C" void kernel_launch(void* const* d_in, const int* in_sizes, int n_in,
                              void* d_out, int out_size, void* d_ws, size_t ws_size,
                              hipStream_t stream) {
    const float* emb    = (const float*)d_in[0];
    const int*   labels = (const int*)d_in[1];
    float*       out    = (float*)d_out;

    char* ws = (char*)d_ws;
    float*         termSum   = (float*)(ws + WS_TERS);
    float*         cntF      = (float*)(ws + WS_CNTF);
    float*         denomPart = (float*)(ws + WS_DENOM);
    int*           posCnt    = (int*)(ws + WS_POSCNT);
    float*         posS      = (float*)(ws + WS_POSS);
    unsigned char* embF      = (unsigned char*)(ws + WS_EMBF);

    k0_convert<<<dim3(B_N * D_K / 8 / 256), dim3(256), 0, stream>>>(emb, embF);

    k1_denom<<<dim3(NTILES), dim3(256), 0, stream>>>(embF, labels, denomPart, posCnt, posS);

    k2_pos<<<dim3(B_N / 4), dim3(256), 0, stream>>>(denomPart, posCnt, posS, termSum, cntF);

    k3_final<<<dim3(1), dim3(256), 0, stream>>>(termSum, cntF, out);
}